// Round 6
// baseline (168.573 us; speedup 1.0000x reference)
//
#include <hip/hip_runtime.h>
#include <hip/hip_bf16.h>
#include <math.h>

#define B_ 256
#define D_ 512
#define C_ 100000
#define BN 32

#define SCALE_  64.0f
#define ALPHA_  1.2f
// THRESH = cos(pi - 0.5), MM = sin(pi - 0.5) * 0.5
#define THRESH_ (-0.8775825618903728f)
#define MM_     (0.23971276930210156f)
#define COSM_   (0.8775825618903728f)   // cos(0.5)
#define SINM_   (0.4794255386042030f)   // sin(0.5)

typedef __bf16 bf16x8 __attribute__((ext_vector_type(8)));
typedef float  f32x4  __attribute__((ext_vector_type(4)));

// ---------------------------------------------------------------------------
// prep: normalize input rows -> bf16 in MFMA-A-frag-linear layout
// (1 KiB tiles; tile_idx = rowtile*16 + ktile; lane (b&15)+((l&3)<<4)).
// Also a_lb + canonical labels.
// ---------------------------------------------------------------------------
__global__ void prep_kernel(const float* __restrict__ inp,
                            const int* __restrict__ lab_raw,
                            const float* __restrict__ weight,
                            __bf16* __restrict__ xnf,
                            float* __restrict__ a_lb,
                            int* __restrict__ lab32) {
    const int b = blockIdx.x;
    const int l = threadIdx.x;   // 0..63  (covers cols l*8 .. l*8+7)

    const bool is64 = (lab_raw[1] == 0) & (lab_raw[3] == 0) & (lab_raw[5] == 0) &
                      (lab_raw[7] == 0) & (lab_raw[9] == 0) & (lab_raw[11] == 0) &
                      (lab_raw[13] == 0) & (lab_raw[15] == 0);
    const int lab = is64 ? lab_raw[2 * b] : lab_raw[b];

    const float* ip = inp + b * D_ + l * 8;
    f32x4 v0 = *(const f32x4*)ip;
    f32x4 v1 = *(const f32x4*)(ip + 4);
    float ss = v0.x * v0.x + v0.y * v0.y + v0.z * v0.z + v0.w * v0.w +
               v1.x * v1.x + v1.y * v1.y + v1.z * v1.z + v1.w * v1.w;
#pragma unroll
    for (int m = 1; m < 64; m <<= 1) ss += __shfl_xor(ss, m);
    const float ninv = 1.0f / fmaxf(sqrtf(ss), 1e-12f);

    float xf[8] = {v0.x * ninv, v0.y * ninv, v0.z * ninv, v0.w * ninv,
                   v1.x * ninv, v1.y * ninv, v1.z * ninv, v1.w * ninv};
    bf16x8 xv;
#pragma unroll
    for (int i = 0; i < 8; ++i) xv[i] = (__bf16)xf[i];

    const int tile_idx = (b >> 4) * 16 + (l >> 2);
    const int lf = (b & 15) + ((l & 3) << 4);
    *(bf16x8*)((char*)xnf + tile_idx * 1024 + lf * 16) = xv;

    const float* wp = weight + (size_t)lab * D_ + l * 8;
    f32x4 w0 = *(const f32x4*)wp;
    f32x4 w1 = *(const f32x4*)(wp + 4);
    float wss = w0.x * w0.x + w0.y * w0.y + w0.z * w0.z + w0.w * w0.w +
                w1.x * w1.x + w1.y * w1.y + w1.z * w1.z + w1.w * w1.w;
    float dp = xf[0] * w0.x + xf[1] * w0.y + xf[2] * w0.z + xf[3] * w0.w +
               xf[4] * w1.x + xf[5] * w1.y + xf[6] * w1.z + xf[7] * w1.w;
#pragma unroll
    for (int m = 1; m < 64; m <<= 1) {
        wss += __shfl_xor(wss, m);
        dp  += __shfl_xor(dp, m);
    }
    if (l == 0) {
        const float cos_lb = dp / fmaxf(sqrtf(wss), 1e-12f);
        const float ccl = fminf(fmaxf(cos_lb, -1.0f), 1.0f);
        const float s = sqrtf(fmaxf(0.0f, 1.0f - ccl * ccl));
        const float a1 = ccl * COSM_ - s * SINM_;
        a_lb[b] = (cos_lb > THRESH_) ? a1 : (cos_lb - MM_);
        lab32[b] = lab;
    }
}

// ---------------------------------------------------------------------------
// Sync-free GEMM + epilogue. Block = 256 threads (4 waves), M=256 x BN=32.
// Wave w: rows w*64..+63, all 32 cols. NO LDS, NO barriers: each wave loads
// its W-fragments directly from global (f32, frag-layout 16-row pattern),
// converts to bf16 in-register; A-frags from L2-resident frag-linear xnf.
// The unrolled K-loop keeps ~2 K-steps (~16 KB/wave) of loads in flight;
// 12 waves/CU of independent streams -> continuous HBM demand.
// Row sumsq fused: lane lr accumulates exactly the rows whose cols it stores.
// ---------------------------------------------------------------------------
__global__ __launch_bounds__(256, 3)
void gemm_kernel(const __bf16* __restrict__ xnf,
                 const float* __restrict__ weight,
                 const float* __restrict__ a_lb,
                 const int* __restrict__ lab32,
                 float* __restrict__ out) {
    const int tid  = threadIdx.x;
    const int lane = tid & 63;
    const int w    = tid >> 6;      // 0..3
    const int n0   = blockIdx.x * BN;
    const int lr   = lane & 15;     // frag row (= C column within n-tile)
    const int lk   = lane >> 4;     // frag k-chunk (0..3)

    f32x4 acc[4][2] = {};
    float ssq[2] = {0.0f, 0.0f};

    // W base for this lane: rows n0+lr (+16 for n=1), k-chunk lk*8
    const float* wb = weight + (size_t)(n0 + lr) * D_ + lk * 8;
    const char*  ab = (const char*)xnf + (size_t)(w * 4 * 16) * 1024 + lane * 16;

#pragma unroll
    for (int kt = 0; kt < 8; ++kt) {
        // ---- W frags: 8 x dwordx4 (1 KiB/wave-instr), f32 -> bf16 + sumsq
        bf16x8 bw[2][2];   // [ks][n]
#pragma unroll
        for (int n = 0; n < 2; ++n) {
#pragma unroll
            for (int ks = 0; ks < 2; ++ks) {
                const float* p = wb + (size_t)n * 16 * D_ + kt * 64 + ks * 32;
                f32x4 lo = *(const f32x4*)(p);
                f32x4 hi = *(const f32x4*)(p + 4);
                ssq[n] += lo.x * lo.x + lo.y * lo.y + lo.z * lo.z + lo.w * lo.w +
                          hi.x * hi.x + hi.y * hi.y + hi.z * hi.z + hi.w * hi.w;
                bf16x8 h;
                h[0] = (__bf16)lo.x; h[1] = (__bf16)lo.y;
                h[2] = (__bf16)lo.z; h[3] = (__bf16)lo.w;
                h[4] = (__bf16)hi.x; h[5] = (__bf16)hi.y;
                h[6] = (__bf16)hi.z; h[7] = (__bf16)hi.w;
                bw[ks][n] = h;
            }
        }
        // ---- A frags: 8 x 16 B (L2-resident, frag-linear)
        bf16x8 af[2][4];
#pragma unroll
        for (int m = 0; m < 4; ++m)
#pragma unroll
            for (int ks = 0; ks < 2; ++ks)
                af[ks][m] = *(const bf16x8*)(ab + ((size_t)m * 16 + kt * 2 + ks) * 1024);

        // ---- 16 MFMA
#pragma unroll
        for (int ks = 0; ks < 2; ++ks)
#pragma unroll
            for (int m = 0; m < 4; ++m)
#pragma unroll
                for (int n = 0; n < 2; ++n)
                    acc[m][n] = __builtin_amdgcn_mfma_f32_16x16x32_bf16(
                        af[ks][m], bw[ks][n], acc[m][n], 0, 0, 0);
    }

    // ---- finish row norms: lanes {l, l^16, l^32, l^48} hold disjoint
    // k-chunks of rows n*16+lr; after reduce every lane has the full sums.
#pragma unroll
    for (int n = 0; n < 2; ++n) {
        ssq[n] += __shfl_xor(ssq[n], 16);
        ssq[n] += __shfl_xor(ssq[n], 32);
    }

    // ---- epilogue
    float al_r[16];
    int   lb_r[16];
    const int rb0 = w * 64 + (lk << 2);
#pragma unroll
    for (int m = 0; m < 4; ++m)
#pragma unroll
        for (int j = 0; j < 4; ++j) {
            al_r[m * 4 + j] = a_lb[rb0 + m * 16 + j];
            lb_r[m * 4 + j] = lab32[rb0 + m * 16 + j];
        }

#pragma unroll
    for (int n = 0; n < 2; ++n) {
        const int c = n0 + n * 16 + lr;
        const float winv = 1.0f / fmaxf(sqrtf(ssq[n]), 1e-12f);
#pragma unroll
        for (int m = 0; m < 4; ++m)
#pragma unroll
            for (int j = 0; j < 4; ++j) {
                const float al = al_r[m * 4 + j];
                const float cosv = acc[m][n][j] * winv;
                const float d = cosv - al;
                const float t = ALPHA_ * __expf(-0.5f * d * d);  // SIGMA = 2
                const float o = (c == lb_r[m * 4 + j]) ? al : (t * cosv + t - 1.0f);
                out[(size_t)(rb0 + m * 16 + j) * C_ + c] = SCALE_ * o;
            }
    }
}

extern "C" void kernel_launch(void* const* d_in, const int* in_sizes, int n_in,
                              void* d_out, int out_size, void* d_ws, size_t ws_size,
                              hipStream_t stream) {
    const float* inp = (const float*)d_in[0];
    const int*   lab = (const int*)d_in[1];
    const float* w   = (const float*)d_in[2];
    float* out = (float*)d_out;

    char* ws = (char*)d_ws;
    __bf16* xnf  = (__bf16*)ws;                       // 262144 B
    float*  a_lb = (float*)(ws + 262144);             // 1 KiB
    int*    l32  = (int*)(ws + 262144 + 1024);        // 1 KiB

    prep_kernel<<<B_, 64, 0, stream>>>(inp, lab, w, xnf, a_lb, l32);
    gemm_kernel<<<C_ / BN, 256, 0, stream>>>(xnf, w, a_lb, l32, out);
}

// Round 8
// 97.142 us; speedup vs baseline: 1.7353x; 1.7353x over previous
//
#include <hip/hip_runtime.h>
#include <hip/hip_bf16.h>
#include <math.h>

#define B_ 256
#define D_ 512
#define C_ 100000
#define BN 32
#define BK 128

#define SCALE_  64.0f
#define ALPHA_  1.2f
// THRESH = cos(pi - 0.5), MM = sin(pi - 0.5) * 0.5
#define THRESH_ (-0.8775825618903728f)
#define MM_     (0.23971276930210156f)
#define COSM_   (0.8775825618903728f)   // cos(0.5)
#define SINM_   (0.4794255386042030f)   // sin(0.5)

typedef __bf16 bf16x8 __attribute__((ext_vector_type(8)));
typedef __bf16 bf16x4 __attribute__((ext_vector_type(4)));
typedef float  f32x4  __attribute__((ext_vector_type(4)));

#define SB()     __builtin_amdgcn_sched_barrier(0)
#define BAR()    __builtin_amdgcn_s_barrier()
#define WAITV(n) asm volatile("s_waitcnt vmcnt(" #n ")" ::: "memory")
#define WAITL0() asm volatile("s_waitcnt lgkmcnt(0)" ::: "memory")

// ---------------------------------------------------------------------------
// prep: normalize input rows -> bf16 in MFMA-A-frag-linear layout
// (1 KiB tiles; tile_idx = rowtile*16 + ktile; lane (b&15)+((l&3)<<4)).
// Also a_lb + canonical labels.
// ---------------------------------------------------------------------------
__global__ void prep_kernel(const float* __restrict__ inp,
                            const int* __restrict__ lab_raw,
                            const float* __restrict__ weight,
                            __bf16* __restrict__ xnf,
                            float* __restrict__ a_lb,
                            int* __restrict__ lab32) {
    const int b = blockIdx.x;
    const int l = threadIdx.x;   // 0..63

    const bool is64 = (lab_raw[1] == 0) & (lab_raw[3] == 0) & (lab_raw[5] == 0) &
                      (lab_raw[7] == 0) & (lab_raw[9] == 0) & (lab_raw[11] == 0) &
                      (lab_raw[13] == 0) & (lab_raw[15] == 0);
    const int lab = is64 ? lab_raw[2 * b] : lab_raw[b];

    const float* ip = inp + b * D_ + l * 8;
    f32x4 v0 = *(const f32x4*)ip;
    f32x4 v1 = *(const f32x4*)(ip + 4);
    float ss = v0.x * v0.x + v0.y * v0.y + v0.z * v0.z + v0.w * v0.w +
               v1.x * v1.x + v1.y * v1.y + v1.z * v1.z + v1.w * v1.w;
#pragma unroll
    for (int m = 1; m < 64; m <<= 1) ss += __shfl_xor(ss, m);
    const float ninv = 1.0f / fmaxf(sqrtf(ss), 1e-12f);

    float xf[8] = {v0.x * ninv, v0.y * ninv, v0.z * ninv, v0.w * ninv,
                   v1.x * ninv, v1.y * ninv, v1.z * ninv, v1.w * ninv};
    bf16x8 xv;
#pragma unroll
    for (int i = 0; i < 8; ++i) xv[i] = (__bf16)xf[i];

    const int tile_idx = (b >> 4) * 16 + (l >> 2);
    const int lf = (b & 15) + ((l & 3) << 4);
    *(bf16x8*)((char*)xnf + tile_idx * 1024 + lf * 16) = xv;

    const float* wp = weight + (size_t)lab * D_ + l * 8;
    f32x4 w0 = *(const f32x4*)wp;
    f32x4 w1 = *(const f32x4*)(wp + 4);
    float wss = w0.x * w0.x + w0.y * w0.y + w0.z * w0.z + w0.w * w0.w +
                w1.x * w1.x + w1.y * w1.y + w1.z * w1.z + w1.w * w1.w;
    float dp = xf[0] * w0.x + xf[1] * w0.y + xf[2] * w0.z + xf[3] * w0.w +
               xf[4] * w1.x + xf[5] * w1.y + xf[6] * w1.z + xf[7] * w1.w;
#pragma unroll
    for (int m = 1; m < 64; m <<= 1) {
        wss += __shfl_xor(wss, m);
        dp  += __shfl_xor(dp, m);
    }
    if (l == 0) {
        const float cos_lb = dp / fmaxf(sqrtf(wss), 1e-12f);
        const float ccl = fminf(fmaxf(cos_lb, -1.0f), 1.0f);
        const float s = sqrtf(fmaxf(0.0f, 1.0f - ccl * ccl));
        const float a1 = ccl * COSM_ - s * SINM_;
        a_lb[b] = (cos_lb > THRESH_) ? a1 : (cos_lb - MM_);
        lab32[b] = lab;
    }
}

// ---------------------------------------------------------------------------
// GEMM + epilogue. 256 thr (4 waves), M=256 x BN=32, 4 K-tiles of BK=128.
// ALL loads are plain global_load_dwordx4 -> VGPR (one homogeneous vmcnt
// FIFO, in-order retirement per m135). 2-tile-deep pipeline with counted
// vmcnt(20): per tile, retire tile t's 20 ops (W 4 + A 16), leave tile
// t+1's 20 in flight across the barrier. W cvt'd f32->bf16 in regs, written
// to XOR-swizzled bf16 LDS (write+read same involution, byte ^= (row&7)<<4
// at 16B granularity). One raw barrier per tile (lgkmcnt(0) first).
// ---------------------------------------------------------------------------
__global__ __launch_bounds__(256, 2)
void gemm_kernel(const __bf16* __restrict__ xnf,
                 const float* __restrict__ weight,
                 const float* __restrict__ a_lb,
                 const int* __restrict__ lab32,
                 float* __restrict__ out) {
    __shared__ __align__(16) char wbuf[2][BN * BK * 2];   // 2 x 8 KiB (bf16)

    const int tid  = threadIdx.x;
    const int lane = tid & 63;
    const int w    = tid >> 6;      // 0..3
    const int n0   = blockIdx.x * BN;
    const int lr   = lane & 15;     // frag row (C column within n-tile)
    const int lk   = lane >> 4;     // frag k-group

    f32x4 acc[4][2] = {};
    float ssq[2] = {0.0f, 0.0f};

    // per-lane staging geometry (wave w stages W rows w*8..w*8+7)
    const int rp_base = w * 8 + (lane >> 5);   // + 2*j
    const int cc      = lane & 31;             // f32x4 chunk within 128-k tile
    const char* ab = (const char*)xnf + (size_t)(w * 4) * 16 * 1024 + lane * 16;

    f32x4  wv0[4], wv1[4];
    bf16x8 afA[4][4], afB[4][4];

    auto issueW = [&](int t, f32x4* wv) {
#pragma unroll
        for (int j = 0; j < 4; ++j) {
            const int rp = rp_base + 2 * j;
            wv[j] = *(const f32x4*)(weight + (size_t)(n0 + rp) * D_ + t * BK + cc * 4);
        }
    };
    auto issueA = [&](int t, bf16x8 (&af)[4][4]) {
#pragma unroll
        for (int m = 0; m < 4; ++m)
#pragma unroll
            for (int ks = 0; ks < 4; ++ks)
                af[m][ks] = *(const bf16x8*)(ab + ((size_t)(m * 16) + t * 4 + ks) * 1024);
    };
    auto cvtWrite = [&](const f32x4* wv, char* buf) {
#pragma unroll
        for (int j = 0; j < 4; ++j) {
            const int rp = rp_base + 2 * j;
            f32x4 v = wv[j];
            bf16x4 h;
            h[0] = (__bf16)v.x; h[1] = (__bf16)v.y;
            h[2] = (__bf16)v.z; h[3] = (__bf16)v.w;
            const int byte = rp * 256 + ((((cc >> 1) ^ (rp & 7))) << 4) + ((cc & 1) << 3);
            *(bf16x4*)(buf + byte) = h;
        }
    };
    auto compute = [&](const char* buf, bf16x8 (&af)[4][4]) {
#pragma unroll
        for (int ks = 0; ks < 4; ++ks) {
            bf16x8 bw[2];
#pragma unroll
            for (int n = 0; n < 2; ++n) {
                const int row = n * 16 + lr;
                const int c16 = (ks * 4 + lk) ^ (lr & 7);
                bw[n] = *(const bf16x8*)(buf + row * 256 + c16 * 16);
                float s = 0.0f;
#pragma unroll
                for (int q = 0; q < 8; ++q) {
                    const float v = (float)bw[n][q];
                    s += v * v;
                }
                ssq[n] += s;
            }
#pragma unroll
            for (int m = 0; m < 4; ++m)
#pragma unroll
                for (int n = 0; n < 2; ++n)
                    acc[m][n] = __builtin_amdgcn_mfma_f32_16x16x32_bf16(
                        af[m][ks], bw[n], acc[m][n], 0, 0, 0);
        }
    };

    // ---- prologue: FIFO = [W0(4) A0(16) W1(4) A1(16)]
    issueW(0, wv0); issueA(0, afA); SB();
    issueW(1, wv1); issueA(1, afB); SB();

    // ---- t0: retire W0+A0 (20 oldest), leave W1+A1 in flight
    WAITV(20); SB();
    cvtWrite(wv0, wbuf[0]);
    WAITL0(); BAR(); SB();
    compute(wbuf[0], afA);
    SB();
    issueW(2, wv0); issueA(2, afA); SB();   // FIFO: [W1 A1 W2 A2]

    // ---- t1
    WAITV(20); SB();
    cvtWrite(wv1, wbuf[1]);
    WAITL0(); BAR(); SB();
    compute(wbuf[1], afB);
    SB();
    issueW(3, wv1); issueA(3, afB); SB();   // FIFO: [W2 A2 W3 A3]

    // ---- t2
    WAITV(20); SB();
    cvtWrite(wv0, wbuf[0]);
    WAITL0(); BAR(); SB();
    compute(wbuf[0], afA);
    SB();

    // ---- t3 (drain)
    WAITV(0); SB();
    cvtWrite(wv1, wbuf[1]);
    WAITL0(); BAR(); SB();
    compute(wbuf[1], afB);

    // ---- finish row norms: lanes {l, l^16, l^32, l^48} hold disjoint
    // k-chunks of rows n*16+lr; after reduce every lane has full sums.
#pragma unroll
    for (int n = 0; n < 2; ++n) {
        ssq[n] += __shfl_xor(ssq[n], 16);
        ssq[n] += __shfl_xor(ssq[n], 32);
    }

    // ---- epilogue
    float al_r[16];
    int   lb_r[16];
    const int rb0 = w * 64 + (lk << 2);
#pragma unroll
    for (int m = 0; m < 4; ++m)
#pragma unroll
        for (int j = 0; j < 4; ++j) {
            al_r[m * 4 + j] = a_lb[rb0 + m * 16 + j];
            lb_r[m * 4 + j] = lab32[rb0 + m * 16 + j];
        }

#pragma unroll
    for (int n = 0; n < 2; ++n) {
        const int c = n0 + n * 16 + lr;
        const float winv = 1.0f / fmaxf(sqrtf(ssq[n]), 1e-12f);
#pragma unroll
        for (int m = 0; m < 4; ++m)
#pragma unroll
            for (int j = 0; j < 4; ++j) {
                const float al = al_r[m * 4 + j];
                const float cosv = acc[m][n][j] * winv;
                const float d = cosv - al;
                const float t = ALPHA_ * __expf(-0.5f * d * d);  // SIGMA = 2
                const float o = (c == lb_r[m * 4 + j]) ? al : (t * cosv + t - 1.0f);
                out[(size_t)(rb0 + m * 16 + j) * C_ + c] = SCALE_ * o;
            }
    }
}

extern "C" void kernel_launch(void* const* d_in, const int* in_sizes, int n_in,
                              void* d_out, int out_size, void* d_ws, size_t ws_size,
                              hipStream_t stream) {
    const float* inp = (const float*)d_in[0];
    const int*   lab = (const int*)d_in[1];
    const float* w   = (const float*)d_in[2];
    float* out = (float*)d_out;

    char* ws = (char*)d_ws;
    __bf16* xnf  = (__bf16*)ws;                       // 262144 B
    float*  a_lb = (float*)(ws + 262144);             // 1 KiB
    int*    l32  = (int*)(ws + 262144 + 1024);        // 1 KiB

    prep_kernel<<<B_, 64, 0, stream>>>(inp, lab, w, xnf, a_lb, l32);
    gemm_kernel<<<C_ / BN, 256, 0, stream>>>(xnf, w, a_lb, l32, out);
}